// Round 5
// baseline (123.217 us; speedup 1.0000x reference)
//
#include <hip/hip_runtime.h>
#include <math.h>

// Adder2D: out[n,co,h,w] = -sum_{ci,kh,kw} |x[n,ci,h+kh-1,w+kw-1] - w[co,ci,kh,kw]|
// x: [16,64,32,32] f32, w: [64,64,3,3] f32, out: [16,64,32,32] f32, pad=1 stride=1.
//
// R5: fix the two measured sinks from R1-R4.
//  (a) Bank conflicts (R4: 5.04M cyc) came from blocked pixels: adjacent
//      lanes 16B apart -> each b128 phase = 32 lanes on 8 banks (4-way).
//      Now pixels are STRIDED: thread u owns cols {u, u+8, u+16, u+24}; every
//      inner x-read is a b32 whose bank map is (8*rl+u) = tid mod 32 -- a
//      perfect permutation per half-wave. Zero conflicts by construction.
//  (b) VALU issue measured ~2.4x the 2-inst/elem model (abs not folded).
//      Inner op forced via inline asm: v_sub_f32 + v_add_f32 with abs()
//      source modifier = exactly 2 insts/elem-op.
//  Also: +1-column zero-pad inside LDS kills all halo cndmasks; one
//  loop-invariant vaddr serves every ds_read via compile-time immediate
//  offsets (no in-loop address math).
// Block 256 thr = 16 co x 8 rows x 32 cols (16 out/thread); ci split in half
// across grid.z; halves combined with hardware fp32 atomics into zeroed out.
// Grid (4,4,32) = 512 blocks = 2/CU = 8 waves/CU.

#define N_   16
#define CI_  64
#define CO_  64
#define HW_  32
#define CG   4     // co per thread
#define COB  16    // co per block
#define PXK  4     // pixels per thread (stride 8)
#define RG   8     // pixel rows per block
#define CIH  32    // ci per block (ci-split x2)
#define CIC  16    // planes staged per round
#define RST  40    // LDS row stride in floats

__global__ __launch_bounds__(256, 2) void adder2d_kernel(
    const float* __restrict__ x, const float* __restrict__ w,
    float* __restrict__ out)
{
    __shared__ __align__(16) float xs[CIC][RG + 2][RST];   // 25600 B
    __shared__ __align__(16) float ws[CIH * 9 * COB];      // 18432 B

    const int tid   = threadIdx.x;
    const int u     = tid & 7;           // pixel cols u+8k
    const int rl    = (tid >> 3) & 7;    // pixel row
    const int cosub = tid >> 6;          // co quad (wave-uniform)
    const int r0    = blockIdx.x * RG;
    const int co0   = blockIdx.y * COB;
    const int n     = blockIdx.z & 15;
    const int ch    = blockIdx.z >> 4;   // ci half

    // ---- zero all of xs once: row/col pads persist; staged cells are
    // overwritten every round (same cells each round) ----
    for (int i = tid; i < CIC * (RG + 2) * RST / 4; i += 256)
        ((float4*)xs)[i] = float4{0.f, 0.f, 0.f, 0.f};

    // ---- stage w for our ci-half: ws[(cil*9+t)*COB+cl] = w[co0+cl][ci][t] ----
    for (int i = tid; i < COB * CIH * 9; i += 256) {
        int cl  = i / (CIH * 9);
        int rem = i - cl * (CIH * 9);          // = cil*9 + t
        ws[rem * COB + cl] = w[(co0 + cl) * (CI_ * 9) + ch * (CIH * 9) + rem];
    }

    float acc[PXK][CG];
#pragma unroll
    for (int k = 0; k < PXK; ++k)
#pragma unroll
        for (int j = 0; j < CG; ++j) acc[k][j] = 0.f;

    const float* xn = x + ((size_t)n * CI_ + ch * CIH) * (HW_ * HW_);

    for (int round = 0; round < CIH / CIC; ++round) {
        __syncthreads();   // previous round's readers done; also publishes zeros/w
        // ---- stage CIC planes, rows r0-1..r0+8 -> xs[p][rr][1+col] ----
        // b32 writes, lanes col-fastest -> conflict-free; coalesced global b32.
#pragma unroll
        for (int p = 0; p < CIC; ++p) {
            for (int i2 = tid; i2 < (RG + 2) * HW_; i2 += 256) {
                int rr  = i2 >> 5, col = i2 & 31;
                int gr  = r0 - 1 + rr;
                if ((unsigned)gr < HW_)
                    xs[p][rr][1 + col] =
                        xn[(size_t)(round * CIC + p) * (HW_ * HW_) + gr * HW_ + col];
            }
        }
        __syncthreads();

#pragma unroll 4
        for (int cil = 0; cil < CIC; ++cil) {
            const int cib = round * CIC + cil;
            const float* wr = &ws[(cib * 9) * COB + cosub * CG];

            // 9 b128 wave-broadcasts (vaddr uniform per wave)
            float4 wv[9];
#pragma unroll
            for (int t = 0; t < 9; ++t)
                wv[t] = *(const float4*)&wr[t * COB];

#pragma unroll
            for (int kh = 0; kh < 3; ++kh) {
                // padded col for pixel u+8k, tap kw is (u+8k)+kw: pad+1, tap-1 cancel
                const float* row = &xs[cil][rl + kh][u];
                float xv[PXK][3];
#pragma unroll
                for (int k = 0; k < PXK; ++k)
#pragma unroll
                    for (int d = 0; d < 3; ++d)
                        xv[k][d] = row[8 * k + d];   // b32, tid-linear banks, imm offsets

#pragma unroll
                for (int kw = 0; kw < 3; ++kw) {
                    const float* wj = (const float*)&wv[kh * 3 + kw];
#pragma unroll
                    for (int j = 0; j < CG; ++j)
#pragma unroll
                        for (int k = 0; k < PXK; ++k) {
                            float dd;
                            asm("v_sub_f32 %1, %2, %3\n\t"
                                "v_add_f32 %0, %0, abs(%1)"
                                : "+v"(acc[k][j]), "=&v"(dd)
                                : "v"(xv[k][kw]), "v"(wj[j]));
                        }
                }
            }
        }
    }

    // ---- combine ci-halves: hardware fp32 atomics into zeroed out ----
    float* op = out + (((size_t)n * CO_ + co0 + cosub * CG) * HW_ + (r0 + rl)) * HW_ + u;
#pragma unroll
    for (int j = 0; j < CG; ++j)
#pragma unroll
        for (int k = 0; k < PXK; ++k)
            unsafeAtomicAdd(&op[(size_t)j * HW_ * HW_ + 8 * k], -acc[k][j]);
}

extern "C" void kernel_launch(void* const* d_in, const int* in_sizes, int n_in,
                              void* d_out, int out_size, void* d_ws, size_t ws_size,
                              hipStream_t stream) {
    const float* x  = (const float*)d_in[0];
    const float* wp = (const float*)d_in[1];
    float* out      = (float*)d_out;
    hipMemsetAsync(d_out, 0, (size_t)out_size * sizeof(float), stream);
    dim3 grid(HW_ / RG, CO_ / COB, N_ * 2);   // (4, 4, 32) = 512 blocks
    adder2d_kernel<<<grid, 256, 0, stream>>>(x, wp, out);
}

// Round 6
// 108.604 us; speedup vs baseline: 1.1346x; 1.1346x over previous
//
#include <hip/hip_runtime.h>
#include <math.h>

// Adder2D: out[n,co,h,w] = -sum_{ci,kh,kw} |x[n,ci,h+kh-1,w+kw-1] - w[co,ci,kh,kw]|
// x: [16,64,32,32] f32, w: [64,64,3,3] f32, out: [16,64,32,32] f32, pad=1 stride=1.
//
// R6: R5 was latency-bound, not pipe-bound (VALUBusy 44%, LDS model ~47%,
// both unsaturated; grid=512 capped us at 2 blocks/CU = 8 waves/CU).
//  - ci-split x4 (CIH=16): grid 1024 = 4 blocks/CU = 16 waves/CU. LDS down
//    to 22KB/block so 4 blocks fit. Partials combined via hw fp32 atomics
//    (R4 measured 2.1M atomics = free; now 4.2M).
//  - x-reads paired for ds_read2_b32 merging (consecutive dword offsets off
//    one vaddr), conflict-free tid-linear bank map preserved.
//  - keep from R5: strided pixels (u, u+8, u+16, u+24), inline-asm
//    sub+add-abs 2 insts/elem-op, LDS-only inner loop, imm-offset reads.

#define N_   16
#define CI_  64
#define CO_  64
#define HW_  32
#define CG   4     // co per thread
#define COB  16    // co per block
#define PXK  4     // pixels per thread (stride 8)
#define RG   8     // pixel rows per block
#define CIH  16    // ci per block (ci-split x4)
#define CIC  8     // planes staged per round
#define RST  40    // LDS row stride in floats

__global__ __launch_bounds__(256, 4) void adder2d_kernel(
    const float* __restrict__ x, const float* __restrict__ w,
    float* __restrict__ out)
{
    __shared__ __align__(16) float xs[CIC][RG + 2][RST];   // 8*10*40*4 = 12800 B
    __shared__ __align__(16) float ws[CIH * 9 * COB];      // 16*9*16*4 =  9216 B

    const int tid   = threadIdx.x;
    const int u     = tid & 7;           // pixel cols u+8k
    const int rl    = (tid >> 3) & 7;    // pixel row
    const int cosub = tid >> 6;          // co quad (wave-uniform)
    const int r0    = blockIdx.x * RG;
    const int co0   = blockIdx.y * COB;
    const int n     = blockIdx.z & 15;
    const int ch    = blockIdx.z >> 4;   // ci quarter: ci in [16ch, 16ch+16)

    // ---- zero xs once: pads persist; staged cells overwritten each round ----
    for (int i = tid; i < CIC * (RG + 2) * RST / 4; i += 256)
        ((float4*)xs)[i] = float4{0.f, 0.f, 0.f, 0.f};

    // ---- stage w for our ci-quarter: ws[(cil*9+t)*COB+cl] = w[co0+cl][ci][t] ----
    for (int i = tid; i < COB * CIH * 9; i += 256) {
        int cl  = i / (CIH * 9);
        int rem = i - cl * (CIH * 9);          // = cil*9 + t
        ws[rem * COB + cl] = w[(co0 + cl) * (CI_ * 9) + ch * (CIH * 9) + rem];
    }

    float acc[PXK][CG];
#pragma unroll
    for (int k = 0; k < PXK; ++k)
#pragma unroll
        for (int j = 0; j < CG; ++j) acc[k][j] = 0.f;

    const float* xn = x + ((size_t)n * CI_ + ch * CIH) * (HW_ * HW_);

    for (int round = 0; round < CIH / CIC; ++round) {
        __syncthreads();   // previous round's readers done; also publishes zeros/w
        // ---- stage CIC planes, rows r0-1..r0+8 -> xs[p][rr][1+col] ----
#pragma unroll
        for (int p = 0; p < CIC; ++p) {
            for (int i2 = tid; i2 < (RG + 2) * HW_; i2 += 256) {
                int rr  = i2 >> 5, col = i2 & 31;
                int gr  = r0 - 1 + rr;
                if ((unsigned)gr < HW_)
                    xs[p][rr][1 + col] =
                        xn[(size_t)(round * CIC + p) * (HW_ * HW_) + gr * HW_ + col];
            }
        }
        __syncthreads();

#pragma unroll 4
        for (int cil = 0; cil < CIC; ++cil) {
            const int cib = round * CIC + cil;
            const float* wr = &ws[(cib * 9) * COB + cosub * CG];

            // 9 b128 wave-broadcasts (vaddr wave-uniform)
            float4 wv[9];
#pragma unroll
            for (int t = 0; t < 9; ++t)
                wv[t] = *(const float4*)&wr[t * COB];

#pragma unroll
            for (int kh = 0; kh < 3; ++kh) {
                // padded col for pixel u+8k, tap kw is (u+8k)+kw: pad+1, tap-1 cancel
                const float* row = &xs[cil][rl + kh][u];
                float xv[PXK][3];
#pragma unroll
                for (int k = 0; k < PXK; ++k)
#pragma unroll
                    for (int d = 0; d < 3; ++d)
                        xv[k][d] = row[8 * k + d];   // consecutive dwords -> ds_read2_b32

#pragma unroll
                for (int kw = 0; kw < 3; ++kw) {
                    const float* wj = (const float*)&wv[kh * 3 + kw];
#pragma unroll
                    for (int j = 0; j < CG; ++j)
#pragma unroll
                        for (int k = 0; k < PXK; ++k) {
                            float dd;
                            asm("v_sub_f32 %1, %2, %3\n\t"
                                "v_add_f32 %0, %0, abs(%1)"
                                : "+v"(acc[k][j]), "=&v"(dd)
                                : "v"(xv[k][kw]), "v"(wj[j]));
                        }
                }
            }
        }
    }

    // ---- combine ci-quarters: hardware fp32 atomics into zeroed out ----
    float* op = out + (((size_t)n * CO_ + co0 + cosub * CG) * HW_ + (r0 + rl)) * HW_ + u;
#pragma unroll
    for (int j = 0; j < CG; ++j)
#pragma unroll
        for (int k = 0; k < PXK; ++k)
            unsafeAtomicAdd(&op[(size_t)j * HW_ * HW_ + 8 * k], -acc[k][j]);
}

extern "C" void kernel_launch(void* const* d_in, const int* in_sizes, int n_in,
                              void* d_out, int out_size, void* d_ws, size_t ws_size,
                              hipStream_t stream) {
    const float* x  = (const float*)d_in[0];
    const float* wp = (const float*)d_in[1];
    float* out      = (float*)d_out;
    hipMemsetAsync(d_out, 0, (size_t)out_size * sizeof(float), stream);
    dim3 grid(HW_ / RG, CO_ / COB, N_ * 4);   // (4, 4, 64) = 1024 blocks
    adder2d_kernel<<<grid, 256, 0, stream>>>(x, wp, out);
}